// Round 9
// baseline (280.604 us; speedup 1.0000x reference)
//
#include <hip/hip_runtime.h>
#include <stdint.h>

// out[p,b,o] = sum_i x*w0 + (1-x)*w1 = sum_i x*(w0-w1) + sum_i w1
// R17: R16 (1024B w strips, XCD-paired tiles, MFMA, verified fragments)
// with the wave->fragment map rebalanced from (2m x 16n) to (8m x 4n).
// R16's LDS read pipe (32 ds_read_b64/wave/step = ~2050 cyc/step/CU) was
// co-dominant with HBM (~3050 cyc/step); 4n cuts B-tile reads 4x, paid for
// by 8 AEXPs (register-side VALU, ~300 cyc/SIMD/step -- cheap).
//   Grid 256 = (tile t = 16p x 8og(256 cols)) x (h = b-half), 1 block/CU.
//   Pair (t, t+128) same XCD -> w fetched from HBM ~once (L2 merge).
//   Wave wv: wm=wv&1 m-half (rows h*256+wm*128..+127, 8 m-frags),
//            wn=wv>>1 col-quarter (cols wn*64..+63, 4 n-frags).
//   acc[8][4] f32x4 = 128 VGPR. Staging side unchanged: wave wv streams
//   k-rows 4wv..+3 (1024B strips), d=w0-w1 -> bds[col][44] bf16, colsum(w1)
//   per-thread. 2-step w prefetch; lgkmcnt-only barriers (vmcnt never
//   drained).

#define NP 16
#define NB 512
#define NI 2048
#define NO 2048
#define JW 64               // u32 words per i-row in xp
#define OT 256              // o-columns per block
#define KS 32               // k-rows per step
#define NST (NI / KS)       // 64 steps

typedef __attribute__((ext_vector_type(8))) short short8;
typedef __attribute__((ext_vector_type(4))) float f32x4;

__global__ __launch_bounds__(256) void pack_x_kernel(const float* __restrict__ x,
                                                     uint32_t* __restrict__ xp) {
    const int gtid = blockIdx.x * 256 + threadIdx.x;
    const int row  = gtid >> 6;     // p*NB + b
    const int lane = gtid & 63;
    const float* src = x + (size_t)row * NI;
    unsigned long long* dst = (unsigned long long*)(xp + (size_t)row * JW);
#pragma unroll 4
    for (int k = 0; k < NI / 64; ++k) {
        const float v = src[k * 64 + lane];
        const unsigned long long m = __ballot(v != 0.0f);
        if (lane == 0) dst[k] = m;
    }
}

// bf16 truncation (exact for d in {-1,0,1} and w1 in {0,1})
#define BF16(f) ((uint32_t)(__float_as_uint(f) >> 16))

// issue next step's w: k-rows 4wv..4wv+3, lane cols 4l..4l+3, both mats
#define WISS(s0_, s1_) do {                                                    \
    _Pragma("unroll")                                                          \
    for (int _j = 0; _j < 4; ++_j) {                                           \
        s0_[_j] = *(const f32x4*)(w0n + (size_t)_j * NO);                      \
        s1_[_j] = *(const f32x4*)(w1n + (size_t)_j * NO);                      \
    }                                                                          \
    w0n += (size_t)KS * NO; w1n += (size_t)KS * NO;                            \
} while (0)

// convert a w set -> bf16 d tile rows 4wv..+3 of bds[b_]; colsum(w1).
#define CVT(s0_, s1_, b_) do {                                                 \
    _Pragma("unroll")                                                          \
    for (int _c = 0; _c < 4; ++_c) {                                           \
        const float _d0 = s0_[0][_c] - s1_[0][_c];                             \
        const float _d1 = s0_[1][_c] - s1_[1][_c];                             \
        const float _d2 = s0_[2][_c] - s1_[2][_c];                             \
        const float _d3 = s0_[3][_c] - s1_[3][_c];                             \
        cs[_c] += s1_[0][_c] + s1_[1][_c] + s1_[2][_c] + s1_[3][_c];           \
        uint2 _st;                                                             \
        _st.x = BF16(_d0) | (BF16(_d1) << 16);                                 \
        _st.y = BF16(_d2) | (BF16(_d3) << 16);                                 \
        *(uint2*)&bds[b_][4 * lane + _c][4 * wv] = _st;                        \
    }                                                                          \
} while (0)

// issue next x words (8 m-frag rows' step-word) and bump
#define XISS(xw) do {                                                          \
    _Pragma("unroll")                                                          \
    for (int _mi = 0; _mi < 8; ++_mi) xw[_mi] = xn[_mi * 1024];                \
    xn += 1;                                                                   \
} while (0)

// expand ONE A-frag from a packed-x word: bit -> bf16 {0,1} (R14-verified)
#define AEXP1(dst_, word_) do {                                                \
    const uint32_t _by = ((word_) >> klo8) & 0xFFu;                            \
    union { uint32_t u[4]; short8 s; } _cv;                                    \
    _cv.u[0] = (_by & 1u   ? 0x3F80u : 0u) | (_by & 2u   ? 0x3F800000u : 0u);  \
    _cv.u[1] = (_by & 4u   ? 0x3F80u : 0u) | (_by & 8u   ? 0x3F800000u : 0u);  \
    _cv.u[2] = (_by & 16u  ? 0x3F80u : 0u) | (_by & 32u  ? 0x3F800000u : 0u);  \
    _cv.u[3] = (_by & 64u  ? 0x3F80u : 0u) | (_by & 128u ? 0x3F800000u : 0u);  \
    dst_ = _cv.s;                                                              \
} while (0)

// read this wave's 4 B-frags from bds[b_], then 8m x 4n MFMAs
#define BRDMFMA(xw, b_) do {                                                   \
    union { uint2 q[2]; short8 s; } _bf[4];                                    \
    _Pragma("unroll")                                                          \
    for (int _nj = 0; _nj < 4; ++_nj) {                                        \
        _bf[_nj].q[0] = *(const uint2*)&bds[b_][wn * 64 + _nj * 16 + lanelo][klo8];     \
        _bf[_nj].q[1] = *(const uint2*)&bds[b_][wn * 64 + _nj * 16 + lanelo][klo8 + 4]; \
    }                                                                          \
    _Pragma("unroll")                                                          \
    for (int _mi = 0; _mi < 8; ++_mi) {                                        \
        short8 _af;                                                            \
        AEXP1(_af, xw[_mi]);                                                   \
        _Pragma("unroll")                                                      \
        for (int _nj = 0; _nj < 4; ++_nj)                                      \
            acc[_mi][_nj] = __builtin_amdgcn_mfma_f32_16x16x32_bf16(           \
                _af, _bf[_nj].s, acc[_mi][_nj], 0, 0, 0);                      \
    }                                                                          \
} while (0)

// lgkmcnt-only barrier: LDS visibility without draining the w vmcnt FIFO
#define BARLDS() asm volatile("s_waitcnt lgkmcnt(0)\n\ts_barrier" ::: "memory")

__global__ __launch_bounds__(512, 2) void evo_w5(const float* __restrict__ w,
                                                 const uint32_t* __restrict__ xp,
                                                 float* __restrict__ out) {
    __shared__ __align__(16) uint16_t bds[2][OT][44];  // 44 KB, dbuf d tile
    __shared__ float csl[8][64][4];                    // 8 KB, colsum partials

    const int tid    = threadIdx.x;
    const int lane   = tid & 63;
    const int wv     = __builtin_amdgcn_readfirstlane(tid >> 6);  // 0..7
    const int wm     = wv & 1;                  // m-half within b-half
    const int wn     = wv >> 1;                 // col quarter 0..3
    const int lanelo = lane & 15;
    const int klo8   = (lane >> 4) * 8;
    const int h      = blockIdx.x >> 7;         // b-half 0..1
    const int t      = blockIdx.x & 127;        // tile; pair (t, t+128) same XCD
    const int p      = t >> 3;                  // 0..15
    const int og     = t & 7;                   // 0..7

    const size_t wq = (size_t)NI * NO;
    const float* w0n = w + (size_t)p * wq + (size_t)(4 * wv) * NO
                     + og * OT + 4 * lane;
    const float* w1n = w0n + (size_t)NP * wq;
    const uint32_t* xn = xp + ((size_t)p * NB + h * 256 + wm * 128 + lanelo) * JW;

    f32x4 acc[8][4];
#pragma unroll
    for (int mi = 0; mi < 8; ++mi)
#pragma unroll
        for (int nj = 0; nj < 4; ++nj) acc[mi][nj] = (f32x4)0.0f;
    float cs[4] = {0.0f, 0.0f, 0.0f, 0.0f};

    f32x4 wA0[4], wA1[4], wB0[4], wB1[4];
    uint32_t xwA[8], xwB[8];

    // ---- prologue: w(0),w(1),x(0),x(1) in flight; cvt w(0)->buf0; w(2) ----
    WISS(wA0, wA1);               // w(0)
    WISS(wB0, wB1);               // w(1)
    XISS(xwA); XISS(xwB);         // x(0), x(1)
    CVT(wA0, wA1, 0);             // waits w(0) only
    WISS(wA0, wA1);               // w(2)
    BARLDS();

    // ---- 64 steps, 2/iter; w issue->cvt distance = 2 full steps ----
#pragma unroll 1
    for (int ss = 0; ss < 32; ++ss) {
        {   // even step s = 2ss : buf0, xwA
            BRDMFMA(xwA, 0);
            if (ss < 31) XISS(xwA);            // x(2ss+2)
            CVT(wB0, wB1, 1);                  // w(2ss+1) -> buf1
            if (ss < 31) WISS(wB0, wB1);       // w(2ss+3)
            BARLDS();
        }
        {   // odd step s = 2ss+1 : buf1, xwB
            BRDMFMA(xwB, 1);
            if (ss < 31) XISS(xwB);            // x(2ss+3)
            if (ss < 31) {
                CVT(wA0, wA1, 0);              // w(2ss+2) -> buf0
                if (ss < 30) WISS(wA0, wA1);   // w(2ss+4), last valid = w62
                BARLDS();
            }
        }
    }

    // ---- colsum reduce + epilogue (exact: integers <= 2048) ----
    csl[wv][lane][0] = cs[0]; csl[wv][lane][1] = cs[1];
    csl[wv][lane][2] = cs[2]; csl[wv][lane][3] = cs[3];
    __syncthreads();

    float* obase = out + ((size_t)p * NB + h * 256 + wm * 128) * NO
                 + og * OT + wn * 64;
#pragma unroll
    for (int nj = 0; nj < 4; ++nj) {
        const int colT = wn * 64 + nj * 16 + lanelo;   // col within 256-tile
        float csT = 0.0f;
#pragma unroll
        for (int q = 0; q < 8; ++q) csT += csl[q][colT >> 2][colT & 3];
#pragma unroll
        for (int mi = 0; mi < 8; ++mi) {
            const int r0 = mi * 16 + (lane >> 4) * 4;
            const f32x4 v = acc[mi][nj];
            obase[(size_t)(r0 + 0) * NO + nj * 16 + lanelo] = v[0] + csT;
            obase[(size_t)(r0 + 1) * NO + nj * 16 + lanelo] = v[1] + csT;
            obase[(size_t)(r0 + 2) * NO + nj * 16 + lanelo] = v[2] + csT;
            obase[(size_t)(r0 + 3) * NO + nj * 16 + lanelo] = v[3] + csT;
        }
    }
}

extern "C" void kernel_launch(void* const* d_in, const int* in_sizes, int n_in,
                              void* d_out, int out_size, void* d_ws, size_t ws_size,
                              hipStream_t stream) {
    const float* x = (const float*)d_in[0];   // (16,512,2048) fp32 {0,1}
    const float* w = (const float*)d_in[1];   // (2,16,1,2048,2048) fp32 {0,1}
    float* out     = (float*)d_out;           // (16,512,2048) fp32
    uint32_t* xp   = (uint32_t*)d_ws;         // 2 MB packed x

    pack_x_kernel<<<dim3((NP * NB * 64) / 256), dim3(256), 0, stream>>>(x, xp);
    evo_w5<<<dim3(256), dim3(512), 0, stream>>>(w, xp, out);
}

// Round 10
// 183.494 us; speedup vs baseline: 1.5292x; 1.5292x over previous
//
#include <hip/hip_runtime.h>
#include <stdint.h>

// out[p,b,o] = sum_i x*w0 + (1-x)*w1 = sum_i x*(w0-w1) + sum_i w1
// R18: R16 verbatim (1024B w strips, XCD-paired tiles, MFMA, verified
// fragments, 162.6us) + PAIR LOCKSTEP PACING. R16's pair (t, t+128) reads
// the same 4 MiB w tile; L2 merge only works if the two blocks stay within
// ~4 steps of each other (16 pairs/XCD x 64KB/step vs 4MiB L2). R16 had no
// pacing -> partial merge (evo ~150us sits between paired 75 and unpaired
// 190). Every 4 steps, thread 0 atomicAdds the pair counter and bounded-
// spins until the partner arrives (s_sleep, budget-capped -> timeout =
// plain R16, zero correctness risk). R17's lesson: no register changes --
// pacing touches wave 0 only; other waves pace via the existing barrier.

#define NP 16
#define NB 512
#define NI 2048
#define NO 2048
#define JW 64               // u32 words per i-row in xp
#define OT 256              // o-columns per block
#define KS 32               // k-rows per step
#define NST (NI / KS)       // 64 steps
#define XP_WORDS (NP * NB * JW)   // 524288 u32 = 2 MiB

typedef __attribute__((ext_vector_type(8))) short short8;
typedef __attribute__((ext_vector_type(4))) float f32x4;

__global__ __launch_bounds__(256) void pack_x_kernel(const float* __restrict__ x,
                                                     uint32_t* __restrict__ xp) {
    const int gtid = blockIdx.x * 256 + threadIdx.x;
    const int row  = gtid >> 6;     // p*NB + b
    const int lane = gtid & 63;
    const float* src = x + (size_t)row * NI;
    unsigned long long* dst = (unsigned long long*)(xp + (size_t)row * JW);
#pragma unroll 4
    for (int k = 0; k < NI / 64; ++k) {
        const float v = src[k * 64 + lane];
        const unsigned long long m = __ballot(v != 0.0f);
        if (lane == 0) dst[k] = m;
    }
}

// bf16 truncation (exact for d in {-1,0,1} and w1 in {0,1})
#define BF16(f) ((uint32_t)(__float_as_uint(f) >> 16))

// issue next step's w: k-rows 4wv..4wv+3, lane cols 4l..4l+3, both mats
#define WISS(s0_, s1_) do {                                                    \
    _Pragma("unroll")                                                          \
    for (int _j = 0; _j < 4; ++_j) {                                           \
        s0_[_j] = *(const f32x4*)(w0n + (size_t)_j * NO);                      \
        s1_[_j] = *(const f32x4*)(w1n + (size_t)_j * NO);                      \
    }                                                                          \
    w0n += (size_t)KS * NO; w1n += (size_t)KS * NO;                            \
} while (0)

// convert a w set -> bf16 d tile rows 4wv..+3 of bds[b_]; colsum(w1).
#define CVT(s0_, s1_, b_) do {                                                 \
    _Pragma("unroll")                                                          \
    for (int _c = 0; _c < 4; ++_c) {                                           \
        const float _d0 = s0_[0][_c] - s1_[0][_c];                             \
        const float _d1 = s0_[1][_c] - s1_[1][_c];                             \
        const float _d2 = s0_[2][_c] - s1_[2][_c];                             \
        const float _d3 = s0_[3][_c] - s1_[3][_c];                             \
        cs[_c] += s1_[0][_c] + s1_[1][_c] + s1_[2][_c] + s1_[3][_c];           \
        uint2 _st;                                                             \
        _st.x = BF16(_d0) | (BF16(_d1) << 16);                                 \
        _st.y = BF16(_d2) | (BF16(_d3) << 16);                                 \
        *(uint2*)&bds[b_][4 * lane + _c][4 * wv] = _st;                        \
    }                                                                          \
} while (0)

// issue next x words (2 m-frag rows' step-word) and bump
#define XISS(xw) do {                                                          \
    xw[0] = xn[0]; xw[1] = xn[1024];                                           \
    xn += 1;                                                                   \
} while (0)

// expand A-frags from packed-x words: bit -> bf16 {0,1}  (R14-verified)
#define AEXP(afr, xw) do {                                                     \
    _Pragma("unroll")                                                          \
    for (int _mi = 0; _mi < 2; ++_mi) {                                        \
        const uint32_t _by = (xw[_mi] >> klo8) & 0xFFu;                        \
        union { uint32_t u[4]; short8 s; } _cv;                                \
        _cv.u[0] = (_by & 1u   ? 0x3F80u : 0u) | (_by & 2u   ? 0x3F800000u : 0u); \
        _cv.u[1] = (_by & 4u   ? 0x3F80u : 0u) | (_by & 8u   ? 0x3F800000u : 0u); \
        _cv.u[2] = (_by & 16u  ? 0x3F80u : 0u) | (_by & 32u  ? 0x3F800000u : 0u); \
        _cv.u[3] = (_by & 64u  ? 0x3F80u : 0u) | (_by & 128u ? 0x3F800000u : 0u); \
        afr[_mi] = _cv.s;                                                      \
    }                                                                          \
} while (0)

// read B-frags from bds[b_] (two b64s each; pitch 88B -> ~2-way, free) + MFMA
#define BRDMFMA(afr, b_) do {                                                  \
    _Pragma("unroll")                                                          \
    for (int _nj = 0; _nj < 16; ++_nj) {                                       \
        union { uint2 q[2]; short8 s; } _u;                                    \
        _u.q[0] = *(const uint2*)&bds[b_][_nj * 16 + lanelo][klo8];            \
        _u.q[1] = *(const uint2*)&bds[b_][_nj * 16 + lanelo][klo8 + 4];        \
        _Pragma("unroll")                                                      \
        for (int _mi = 0; _mi < 2; ++_mi)                                      \
            acc[_mi][_nj] = __builtin_amdgcn_mfma_f32_16x16x32_bf16(           \
                afr[_mi], _u.s, acc[_mi][_nj], 0, 0, 0);                       \
    }                                                                          \
} while (0)

// lgkmcnt-only barrier: LDS visibility without draining the w vmcnt FIFO
#define BARLDS() asm volatile("s_waitcnt lgkmcnt(0)\n\ts_barrier" ::: "memory")

// pair lockstep: thread 0 arrives at phase ph_ and bounded-spins for partner.
// Pure perf hint: timeout -> proceed (degenerates to R16). AGENT scope.
#define PACE(ph_) do {                                                         \
    if (tid == 0) {                                                            \
        const uint32_t _tgt = 2u * (uint32_t)(ph_);                            \
        __hip_atomic_fetch_add(&pace[t], 1u, __ATOMIC_RELAXED,                 \
                               __HIP_MEMORY_SCOPE_AGENT);                      \
        int _budget = 200;                                                     \
        while (__hip_atomic_load(&pace[t], __ATOMIC_RELAXED,                   \
                                 __HIP_MEMORY_SCOPE_AGENT) < _tgt              \
               && --_budget > 0)                                               \
            __builtin_amdgcn_s_sleep(2);                                       \
    }                                                                          \
} while (0)

__global__ __launch_bounds__(512, 2) void evo_w4(const float* __restrict__ w,
                                                 const uint32_t* __restrict__ xp,
                                                 uint32_t* __restrict__ pace,
                                                 float* __restrict__ out) {
    __shared__ __align__(16) uint16_t bds[2][OT][44];  // 44 KB, dbuf d tile
    __shared__ float csl[8][64][4];                    // 8 KB, colsum partials

    const int tid    = threadIdx.x;
    const int lane   = tid & 63;
    const int wv     = __builtin_amdgcn_readfirstlane(tid >> 6);  // 0..7
    const int lanelo = lane & 15;
    const int klo8   = (lane >> 4) * 8;
    const int h      = blockIdx.x >> 7;         // b-half 0..1
    const int t      = blockIdx.x & 127;        // tile; pair (t, t+128) same XCD
    const int p      = t >> 3;                  // 0..15
    const int og     = t & 7;                   // 0..7

    const size_t wq = (size_t)NI * NO;
    const float* w0n = w + (size_t)p * wq + (size_t)(4 * wv) * NO
                     + og * OT + 4 * lane;
    const float* w1n = w0n + (size_t)NP * wq;
    const uint32_t* xn = xp + ((size_t)p * NB + h * 256 + wv * 32 + lanelo) * JW;

    f32x4 acc[2][16];
#pragma unroll
    for (int mi = 0; mi < 2; ++mi)
#pragma unroll
        for (int nj = 0; nj < 16; ++nj) acc[mi][nj] = (f32x4)0.0f;
    float cs[4] = {0.0f, 0.0f, 0.0f, 0.0f};

    f32x4 wA0[4], wA1[4], wB0[4], wB1[4];
    uint32_t xwA[2], xwB[2];

    // ---- prologue: w(0),w(1),x(0),x(1) in flight; cvt w(0)->buf0; w(2) ----
    WISS(wA0, wA1);               // w(0)
    WISS(wB0, wB1);               // w(1)
    XISS(xwA); XISS(xwB);         // x(0), x(1)
    CVT(wA0, wA1, 0);             // waits w(0) only
    WISS(wA0, wA1);               // w(2)
    BARLDS();

    // ---- 64 steps, 2/iter; w issue->cvt distance = 2 full steps ----
#pragma unroll 1
    for (int ss = 0; ss < 32; ++ss) {
        if ((ss & 1) == 0) PACE((ss >> 1) + 1);   // every 4 steps
        {   // even step s = 2ss : buf0, xwA
            short8 afr[2];
            AEXP(afr, xwA);
            if (ss < 31) XISS(xwA);            // x(2ss+2)
            BRDMFMA(afr, 0);
            CVT(wB0, wB1, 1);                  // w(2ss+1) -> buf1
            if (ss < 31) WISS(wB0, wB1);       // w(2ss+3)
            BARLDS();
        }
        {   // odd step s = 2ss+1 : buf1, xwB
            short8 afr[2];
            AEXP(afr, xwB);
            if (ss < 31) XISS(xwB);            // x(2ss+3)
            BRDMFMA(afr, 1);
            if (ss < 31) {
                CVT(wA0, wA1, 0);              // w(2ss+2) -> buf0
                if (ss < 30) WISS(wA0, wA1);   // w(2ss+4), last valid = w62
                BARLDS();
            }
        }
    }

    // ---- colsum reduce + epilogue (exact: integers <= 2048) ----
    csl[wv][lane][0] = cs[0]; csl[wv][lane][1] = cs[1];
    csl[wv][lane][2] = cs[2]; csl[wv][lane][3] = cs[3];
    __syncthreads();

    float* obase = out + ((size_t)p * NB + h * 256 + wv * 32) * NO + og * OT;
#pragma unroll
    for (int nj = 0; nj < 16; ++nj) {
        const int colT = nj * 16 + lanelo;
        float csT = 0.0f;
#pragma unroll
        for (int q = 0; q < 8; ++q) csT += csl[q][colT >> 2][colT & 3];
#pragma unroll
        for (int mi = 0; mi < 2; ++mi) {
            const int r0 = mi * 16 + (lane >> 4) * 4;
            const f32x4 v = acc[mi][nj];
            obase[(size_t)(r0 + 0) * NO + colT] = v[0] + csT;
            obase[(size_t)(r0 + 1) * NO + colT] = v[1] + csT;
            obase[(size_t)(r0 + 2) * NO + colT] = v[2] + csT;
            obase[(size_t)(r0 + 3) * NO + colT] = v[3] + csT;
        }
    }
}

extern "C" void kernel_launch(void* const* d_in, const int* in_sizes, int n_in,
                              void* d_out, int out_size, void* d_ws, size_t ws_size,
                              hipStream_t stream) {
    const float* x = (const float*)d_in[0];   // (16,512,2048) fp32 {0,1}
    const float* w = (const float*)d_in[1];   // (2,16,1,2048,2048) fp32 {0,1}
    float* out     = (float*)d_out;           // (16,512,2048) fp32
    uint32_t* xp   = (uint32_t*)d_ws;         // 2 MiB packed x
    uint32_t* pace = xp + XP_WORDS;           // 128 pair counters (512 B)

    hipMemsetAsync(pace, 0, 128 * sizeof(uint32_t), stream);
    pack_x_kernel<<<dim3((NP * NB * 64) / 256), dim3(256), 0, stream>>>(x, xp);
    evo_w4<<<dim3(256), dim3(512), 0, stream>>>(w, xp, pace, out);
}